// Round 9
// baseline (103.221 us; speedup 1.0000x reference)
//
#include <hip/hip_runtime.h>
#include <math.h>

#define HDIM 256
#define H4   64          // HDIM / 4
#define EPSN 1e-8f       // torch F.cosine_similarity norm clamp
#define CT   80          // c-tile per block -> grid = 250 blocks (no CU tail)
#define KC   8           // f4 k-steps per chunk (32 floats)
#define NCH  8           // chunks: KC*NCH = H4

typedef unsigned long long u64;
typedef unsigned int       u32;

// Monotonic (value, index) packing: larger key == better candidate under
// lax.top_k semantics (descending value, lower index wins ties).
__device__ __forceinline__ u64 make_key(float v, int idx) {
    u32 u = __float_as_uint(v);
    u ^= (u & 0x80000000u) ? 0xFFFFFFFFu : 0x80000000u;
    return ((u64)u << 32) | (u32)(~idx);
}
__device__ __forceinline__ float key_val(u64 k) {
    u32 u = (u32)(k >> 32);
    u ^= (u & 0x80000000u) ? 0x80000000u : 0xFFFFFFFFu;
    return __uint_as_float(u);
}
__device__ __forceinline__ int key_idx(u64 k) { return (int)(~(u32)k); }

__device__ __forceinline__ void insert8(u64* ls, u64 k) {
    if (k > ls[7]) {
        ls[7] = k;
        #pragma unroll
        for (int j = 7; j > 0; --j)
            if (ls[j] > ls[j-1]) { u64 tmp = ls[j]; ls[j] = ls[j-1]; ls[j-1] = tmp; }
    }
}

// ---------------------------------------------------------------------------
// Kernel 1 (sims): identical to round 8 (double-buffered LDS).
// ---------------------------------------------------------------------------
__global__ __launch_bounds__(256)
void sims_kernel(const float4* __restrict__ q4, const float4* __restrict__ emb4,
                 float* __restrict__ sims, int C, int B) {
    __shared__ float4 e_lds[2][CT][KC + 1];   // 2 x 11.25 KB
    __shared__ float4 q_lds[2][64][KC + 1];   // 2 x  9.0 KB   (total 41.5 KB)

    const int t  = threadIdx.x;
    const int c0 = blockIdx.x * CT;
    const int tc = t & 15;       // c-rows: tc + 16i, i < 5
    const int tb = t >> 4;       // b-rows: tb + 16j, j < 4
    const float4 z = make_float4(0.f, 0.f, 0.f, 0.f);

    float4 pe0, pe1, pe2, pq0, pq1;

    #define LOAD_E(idx, ch, dst) do {                                        \
        int _r = (idx) >> 3, _cl = (idx) & 7; int _gc = c0 + _r;             \
        dst = (_gc < C) ? emb4[(size_t)_gc * H4 + (ch) * KC + _cl] : z;      \
    } while (0)
    #define LOAD_Q(idx, ch, dst) do {                                        \
        int _r = (idx) >> 3, _cl = (idx) & 7;                                \
        dst = (_r < B) ? q4[(size_t)_r * H4 + (ch) * KC + _cl] : z;          \
    } while (0)
    #define LOAD_CHUNK(ch) do {                                              \
        LOAD_E(t,       ch, pe0); LOAD_E(t + 256, ch, pe1);                  \
        if (t < 128) LOAD_E(t + 512, ch, pe2);                               \
        LOAD_Q(t,       ch, pq0); LOAD_Q(t + 256, ch, pq1);                  \
    } while (0)
    #define WRITE_CHUNK(pp) do {                                             \
        { int r = t >> 3,       cl = t & 7;       e_lds[pp][r][cl] = pe0; }  \
        { int r = (t+256) >> 3, cl = (t+256) & 7; e_lds[pp][r][cl] = pe1; }  \
        if (t < 128) { int r = (t+512) >> 3, cl = (t+512) & 7; e_lds[pp][r][cl] = pe2; } \
        { int r = t >> 3,       cl = t & 7;       q_lds[pp][r][cl] = pq0; }  \
        { int r = (t+256) >> 3, cl = (t+256) & 7; q_lds[pp][r][cl] = pq1; }  \
    } while (0)

    float acc[5][4], ee[5], qq[4];
    #pragma unroll
    for (int i = 0; i < 5; ++i) {
        ee[i] = 0.f;
        #pragma unroll
        for (int j = 0; j < 4; ++j) acc[i][j] = 0.f;
    }
    #pragma unroll
    for (int j = 0; j < 4; ++j) qq[j] = 0.f;

    LOAD_CHUNK(0);
    WRITE_CHUNK(0);
    __syncthreads();

    int p = 0;
    for (int ch = 0; ch < NCH; ++ch) {
        if (ch + 1 < NCH) LOAD_CHUNK(ch + 1);    // global prefetch (async)

        #pragma unroll
        for (int s = 0; s < KC; ++s) {
            float4 a[5], b[4];
            #pragma unroll
            for (int i = 0; i < 5; ++i) a[i] = e_lds[p][tc + 16 * i][s];
            #pragma unroll
            for (int j = 0; j < 4; ++j) b[j] = q_lds[p][tb + 16 * j][s];

            #pragma unroll
            for (int i = 0; i < 5; ++i)
                ee[i] = fmaf(a[i].x,a[i].x, fmaf(a[i].y,a[i].y,
                        fmaf(a[i].z,a[i].z, fmaf(a[i].w,a[i].w, ee[i]))));
            #pragma unroll
            for (int j = 0; j < 4; ++j)
                qq[j] = fmaf(b[j].x,b[j].x, fmaf(b[j].y,b[j].y,
                        fmaf(b[j].z,b[j].z, fmaf(b[j].w,b[j].w, qq[j]))));
            #pragma unroll
            for (int i = 0; i < 5; ++i)
                #pragma unroll
                for (int j = 0; j < 4; ++j)
                    acc[i][j] = fmaf(a[i].x,b[j].x, fmaf(a[i].y,b[j].y,
                                fmaf(a[i].z,b[j].z, fmaf(a[i].w,b[j].w, acc[i][j]))));
        }

        if (ch + 1 < NCH) {
            WRITE_CHUNK(p ^ 1);    // other buffer: no conflict with readers
            __syncthreads();       // single barrier per chunk
            p ^= 1;
        }
    }

    float einv[5], qinv[4];
    #pragma unroll
    for (int i = 0; i < 5; ++i) einv[i] = 1.f / fmaxf(sqrtf(ee[i]), EPSN);
    #pragma unroll
    for (int j = 0; j < 4; ++j) qinv[j] = 1.f / fmaxf(sqrtf(qq[j]), EPSN);

    #pragma unroll
    for (int j = 0; j < 4; ++j) {
        int b = tb + 16 * j;
        if (b < B) {
            #pragma unroll
            for (int i = 0; i < 5; ++i) {
                int c = c0 + tc + 16 * i;
                if (c < C) sims[(size_t)b * C + c] = acc[i][j] * qinv[j] * einv[i];
            }
        }
    }
    #undef WRITE_CHUNK
    #undef LOAD_CHUNK
    #undef LOAD_Q
    #undef LOAD_E
}

// ---------------------------------------------------------------------------
// Kernel 2 (topk_scan): identical to round 8.
// ---------------------------------------------------------------------------
__global__ __launch_bounds__(256)
void topk_scan(const float* __restrict__ sims, const u32* __restrict__ mask4,
               u64* __restrict__ cand, int* __restrict__ flags, int C, int B) {
    const int t = threadIdx.x;

    if (blockIdx.x == (unsigned)(B * 4)) {   // ---- mask layout detection ----
        __shared__ int red0[4], red1[4];
        int lo = 0, lg = 0;
        const int n4 = C >> 2;
        int i = t;
        for (; i + 768 < n4; i += 1024) {
            u32 v0 = mask4[i], v1 = mask4[i + 256], v2 = mask4[i + 512], v3 = mask4[i + 768];
            u32 o = v0 | v1 | v2 | v3;
            if (o & 0xFFFFFF00u) lo = 1;   // nonzero byte at offset 1..3
            if (o & 0xFEFEFEFEu) lg = 1;   // any byte value > 1
        }
        for (; i < n4; i += 256) {
            u32 v = mask4[i];
            if (v & 0xFFFFFF00u) lo = 1;
            if (v & 0xFEFEFEFEu) lg = 1;
        }
        const unsigned char* mb = (const unsigned char*)mask4;
        for (int j = (n4 << 2) + t; j < C; j += 256) {
            unsigned char v = mb[j];
            if (v > 1) lg = 1;
            if ((j & 3) != 0 && v != 0) lo = 1;
        }
        lo = __any(lo); lg = __any(lg);
        if ((t & 63) == 0) { red0[t >> 6] = lo; red1[t >> 6] = lg; }
        __syncthreads();
        if (t == 0) {
            flags[0] = red0[0] | red0[1] | red0[2] | red0[3];
            flags[1] = red1[0] | red1[1] | red1[2] | red1[3];
        }
        return;
    }

    __shared__ u64 sh[256 * 8];   // 16 KB
    const int b    = blockIdx.x >> 2;
    const int seg  = blockIdx.x & 3;
    const int slen = (C + 3) >> 2;
    const int cbeg = seg * slen;
    const int cend = min(cbeg + slen, C);
    const float* row = sims + (size_t)b * C;

    u64 ls[8];
    #pragma unroll
    for (int j = 0; j < 8; ++j) ls[j] = 0ull;

    int c = cbeg + t;
    for (; c + 7 * 256 < cend; c += 8 * 256) {     // 8 independent loads first
        float v[8];
        #pragma unroll
        for (int u = 0; u < 8; ++u) v[u] = row[c + u * 256];
        #pragma unroll
        for (int u = 0; u < 8; ++u) insert8(ls, make_key(v[u], c + u * 256));
    }
    for (; c < cend; c += 256) insert8(ls, make_key(row[c], c));

    #pragma unroll
    for (int j = 0; j < 8; ++j) sh[t * 8 + j] = ls[j];
    __syncthreads();

    if (t < 64) {
        u64 m[8];
        #pragma unroll
        for (int j = 0; j < 8; ++j) m[j] = 0ull;
        for (int tt = 0; tt < 4; ++tt) {
            const u64* pp = &sh[(t * 4 + tt) * 8];
            #pragma unroll
            for (int j = 0; j < 8; ++j) {
                u64 k = pp[j];
                if (k <= m[7]) break;           // pp[] sorted descending
                m[7] = k;
                #pragma unroll
                for (int q = 7; q > 0; --q)
                    if (m[q] > m[q-1]) { u64 tmp = m[q]; m[q] = m[q-1]; m[q-1] = tmp; }
            }
        }
        for (int r = 0; r < 8; ++r) {
            u64 best = m[0];
            #pragma unroll
            for (int off = 32; off; off >>= 1) {
                u64 o = __shfl_xor(best, off, 64);
                if (o > best) best = o;
            }
            if (m[0] == best) {                 // unique owner pops
                #pragma unroll
                for (int q = 0; q < 7; ++q) m[q] = m[q+1];
                m[7] = 0ull;
            }
            if (t == 0) cand[((size_t)b * 4 + seg) * 8 + r] = best;
        }
    }
}

// ---------------------------------------------------------------------------
// Kernel 3 (gather): identical to round 8.
// ---------------------------------------------------------------------------
__global__ __launch_bounds__(256)
void gather_kernel(const float* __restrict__ episodes,    // [C][S][256]
                   const float* __restrict__ compressed,  // [C][Cs][256]
                   const void* __restrict__ is_comp,
                   const u64* __restrict__ cand,          // [B][4][8]
                   const int* __restrict__ flags,
                   float* __restrict__ out,               // [B*8][S*256]
                   float* __restrict__ scores_out,        // [B*8]
                   int S, int Cs) {
    const int bj = blockIdx.x >> 1;
    const int h  = blockIdx.x & 1;
    const int b  = bj >> 3;
    const int j  = bj & 7;

    // merge 32 candidate keys -> top-8 (sorted desc); rank j = ls[j]
    const u64* cb = cand + (size_t)b * 32;
    u64 ls[8];
    #pragma unroll
    for (int q = 0; q < 8; ++q) ls[q] = 0ull;
    #pragma unroll
    for (int i = 0; i < 32; ++i) insert8(ls, cb[i]);

    const u64 kj  = ls[j];
    const int idx = key_idx(kj);
    if (h == 0 && threadIdx.x == 0) scores_out[bj] = key_val(kj);

    const int f_off = flags[0], f_gt1 = flags[1];
    bool comp;
    if      (f_gt1) comp = ((const float*)is_comp)[idx] != 0.f;
    else if (f_off) comp = ((const unsigned char*)is_comp)[idx] != 0;
    else            comp = ((const int*)is_comp)[idx] != 0;

    const int n4   = S * H4;       // 2048
    const int c4   = Cs * H4;      // 1024
    const int half = n4 >> 1;      // 1024
    const int v0   = h * half;

    const float4* full4 = (const float4*)episodes   + (size_t)idx * n4;
    const float4* cmp4  = (const float4*)compressed + (size_t)idx * c4;
    float4* out4 = (float4*)out + (size_t)bj * n4;
    const float4 z = make_float4(0.f, 0.f, 0.f, 0.f);

    if (comp) {
        #pragma unroll 4
        for (int v = v0 + threadIdx.x; v < v0 + half; v += 256)
            out4[v] = (v < c4) ? cmp4[v] : z;
    } else {
        #pragma unroll 4
        for (int v = v0 + threadIdx.x; v < v0 + half; v += 256)
            out4[v] = full4[v];
    }
}

// ---------------------------------------------------------------------------
extern "C" void kernel_launch(void* const* d_in, const int* in_sizes, int n_in,
                              void* d_out, int out_size, void* d_ws, size_t ws_size,
                              hipStream_t stream) {
    const float* query      = (const float*)d_in[0];
    const float* episodes   = (const float*)d_in[1];
    const float* compressed = (const float*)d_in[2];
    const float* emb        = (const float*)d_in[3];
    const void*  is_comp    = d_in[4];
    // d_in[5] is k (device scalar); fixed at 8 by the problem setup.

    const int B  = in_sizes[0] / HDIM;        // 64
    const int C  = in_sizes[3] / HDIM;        // 20000
    const int S  = in_sizes[1] / (C * HDIM);  // 32
    const int Cs = in_sizes[2] / (C * HDIM);  // 16
    const int K  = 8;

    float* out        = (float*)d_out;
    float* scores_out = out + (size_t)B * K * S * HDIM;

    // scratch layout in d_ws (fully rewritten every call -> deterministic):
    float* sims    = (float*)d_ws;                             // B*C floats
    size_t simsOff = (((size_t)B * C * sizeof(float)) + 255) & ~(size_t)255;
    u64*   cand    = (u64*)((char*)d_ws + simsOff);            // B*4*8 u64
    int*   flags   = (int*)(cand + (size_t)B * 32);            // 2 ints

    // ATTRIBUTION ROUND: every kernel launched TWICE (all idempotent).
    //   work           = dur_new - 55.4us
    //   fixed_overhead = 2*55.4us - dur_new
    sims_kernel<<<(C + CT - 1) / CT, 256, 0, stream>>>(
        (const float4*)query, (const float4*)emb, sims, C, B);
    sims_kernel<<<(C + CT - 1) / CT, 256, 0, stream>>>(
        (const float4*)query, (const float4*)emb, sims, C, B);
    topk_scan<<<B * 4 + 1, 256, 0, stream>>>(sims, (const u32*)is_comp,
                                             cand, flags, C, B);
    topk_scan<<<B * 4 + 1, 256, 0, stream>>>(sims, (const u32*)is_comp,
                                             cand, flags, C, B);
    gather_kernel<<<B * K * 2, 256, 0, stream>>>(episodes, compressed, is_comp,
                                                 cand, flags, out, scores_out,
                                                 S, Cs);
    gather_kernel<<<B * K * 2, 256, 0, stream>>>(episodes, compressed, is_comp,
                                                 cand, flags, out, scores_out,
                                                 S, Cs);
}

// Round 10
// 59.137 us; speedup vs baseline: 1.7455x; 1.7455x over previous
//
#include <hip/hip_runtime.h>
#include <math.h>

#define HDIM 256
#define H4   64          // HDIM / 4
#define EPSN 1e-8f       // torch F.cosine_similarity norm clamp
#define CT   80          // c-tile per block -> grid = 250 blocks (no CU tail)
#define GP   20          // c's per top-8 scan group (4 groups x 20 = CT)
#define KC   8           // f4 k-steps per chunk (32 floats)
#define NCH  8           // chunks: KC*NCH = H4

typedef unsigned long long u64;
typedef unsigned int       u32;

// Monotonic (value, index) packing: larger key == better candidate under
// lax.top_k semantics (descending value, lower index wins ties).
__device__ __forceinline__ u64 make_key(float v, int idx) {
    u32 u = __float_as_uint(v);
    u ^= (u & 0x80000000u) ? 0xFFFFFFFFu : 0x80000000u;
    return ((u64)u << 32) | (u32)(~idx);
}
__device__ __forceinline__ float key_val(u64 k) {
    u32 u = (u32)(k >> 32);
    u ^= (u & 0x80000000u) ? 0x80000000u : 0xFFFFFFFFu;
    return __uint_as_float(u);
}
__device__ __forceinline__ int key_idx(u64 k) { return (int)(~(u32)k); }

__device__ __forceinline__ void insert8(u64* ls, u64 k) {
    if (k > ls[7]) {
        ls[7] = k;
        #pragma unroll
        for (int j = 7; j > 0; --j)
            if (ls[j] > ls[j-1]) { u64 tmp = ls[j]; ls[j] = ls[j-1]; ls[j-1] = tmp; }
    }
}

// ---------------------------------------------------------------------------
// Kernel 1 (sims+topk1): main loop IDENTICAL to round 8 (dbuf LDS, 5x4 reg
// tile, fused norms). New epilogue: normalized scores -> LDS (union-aliased
// onto the dead staging buffers), 256 threads scan 20 LDS-resident c's each
// -> per-(b, 20-c-group) top-8 -> cand[b][tile][4][8]. The 5.1MB sims array
// and the separate topk_scan kernel are eliminated.
// ---------------------------------------------------------------------------
__global__ __launch_bounds__(256)
void sims_topk_kernel(const float4* __restrict__ q4,
                      const float4* __restrict__ emb4,
                      u64* __restrict__ cand, int C, int B, int NT) {
    __shared__ union SMu {
        struct St { float4 e[2][CT][KC + 1]; float4 q[2][64][KC + 1]; } st; // 41472 B
        struct Ep { float sc[64][CT + 1]; } ep;                             // 20736 B
    } sm;

    const int t  = threadIdx.x;
    const int c0 = blockIdx.x * CT;
    const int tc = t & 15;       // c-rows: tc + 16i, i < 5
    const int tb = t >> 4;       // b-rows: tb + 16j, j < 4
    const float4 z = make_float4(0.f, 0.f, 0.f, 0.f);

    float4 pe0, pe1, pe2, pq0, pq1;

    #define LOAD_E(idx, ch, dst) do {                                        \
        int _r = (idx) >> 3, _cl = (idx) & 7; int _gc = c0 + _r;             \
        dst = (_gc < C) ? emb4[(size_t)_gc * H4 + (ch) * KC + _cl] : z;      \
    } while (0)
    #define LOAD_Q(idx, ch, dst) do {                                        \
        int _r = (idx) >> 3, _cl = (idx) & 7;                                \
        dst = (_r < B) ? q4[(size_t)_r * H4 + (ch) * KC + _cl] : z;          \
    } while (0)
    #define LOAD_CHUNK(ch) do {                                              \
        LOAD_E(t,       ch, pe0); LOAD_E(t + 256, ch, pe1);                  \
        if (t < 128) LOAD_E(t + 512, ch, pe2);                               \
        LOAD_Q(t,       ch, pq0); LOAD_Q(t + 256, ch, pq1);                  \
    } while (0)
    #define WRITE_CHUNK(pp) do {                                             \
        { int r = t >> 3,       cl = t & 7;       sm.st.e[pp][r][cl] = pe0; }\
        { int r = (t+256) >> 3, cl = (t+256) & 7; sm.st.e[pp][r][cl] = pe1; }\
        if (t < 128) { int r = (t+512) >> 3, cl = (t+512) & 7; sm.st.e[pp][r][cl] = pe2; } \
        { int r = t >> 3,       cl = t & 7;       sm.st.q[pp][r][cl] = pq0; }\
        { int r = (t+256) >> 3, cl = (t+256) & 7; sm.st.q[pp][r][cl] = pq1; }\
    } while (0)

    float acc[5][4], ee[5], qq[4];
    #pragma unroll
    for (int i = 0; i < 5; ++i) {
        ee[i] = 0.f;
        #pragma unroll
        for (int j = 0; j < 4; ++j) acc[i][j] = 0.f;
    }
    #pragma unroll
    for (int j = 0; j < 4; ++j) qq[j] = 0.f;

    LOAD_CHUNK(0);
    WRITE_CHUNK(0);
    __syncthreads();

    int p = 0;
    for (int ch = 0; ch < NCH; ++ch) {
        if (ch + 1 < NCH) LOAD_CHUNK(ch + 1);    // global prefetch (async)

        #pragma unroll
        for (int s = 0; s < KC; ++s) {
            float4 a[5], b[4];
            #pragma unroll
            for (int i = 0; i < 5; ++i) a[i] = sm.st.e[p][tc + 16 * i][s];
            #pragma unroll
            for (int j = 0; j < 4; ++j) b[j] = sm.st.q[p][tb + 16 * j][s];

            #pragma unroll
            for (int i = 0; i < 5; ++i)
                ee[i] = fmaf(a[i].x,a[i].x, fmaf(a[i].y,a[i].y,
                        fmaf(a[i].z,a[i].z, fmaf(a[i].w,a[i].w, ee[i]))));
            #pragma unroll
            for (int j = 0; j < 4; ++j)
                qq[j] = fmaf(b[j].x,b[j].x, fmaf(b[j].y,b[j].y,
                        fmaf(b[j].z,b[j].z, fmaf(b[j].w,b[j].w, qq[j]))));
            #pragma unroll
            for (int i = 0; i < 5; ++i)
                #pragma unroll
                for (int j = 0; j < 4; ++j)
                    acc[i][j] = fmaf(a[i].x,b[j].x, fmaf(a[i].y,b[j].y,
                                fmaf(a[i].z,b[j].z, fmaf(a[i].w,b[j].w, acc[i][j]))));
        }

        if (ch + 1 < NCH) {
            WRITE_CHUNK(p ^ 1);    // other buffer: no conflict with readers
            __syncthreads();       // single barrier per chunk
            p ^= 1;
        }
    }

    float einv[5], qinv[4];
    #pragma unroll
    for (int i = 0; i < 5; ++i) einv[i] = 1.f / fmaxf(sqrtf(ee[i]), EPSN);
    #pragma unroll
    for (int j = 0; j < 4; ++j) qinv[j] = 1.f / fmaxf(sqrtf(qq[j]), EPSN);

    // ---- epilogue: scores -> LDS (reusing staging memory), local top-8 ----
    __syncthreads();               // all waves done reading sm.st
    #pragma unroll
    for (int j = 0; j < 4; ++j) {
        int b = tb + 16 * j;
        if (b < B) {
            #pragma unroll
            for (int i = 0; i < 5; ++i)
                sm.ep.sc[b][tc + 16 * i] = acc[i][j] * qinv[j] * einv[i];
        }
    }
    __syncthreads();

    const int sb = t & 63;         // b
    const int g  = t >> 6;         // c-group (20 c's)
    if (sb < B) {
        u64 ls[8];
        #pragma unroll
        for (int j = 0; j < 8; ++j) ls[j] = 0ull;
        #pragma unroll
        for (int i2 = 0; i2 < GP; ++i2) {
            int cl = g * GP + i2;
            int c  = c0 + cl;
            if (c < C) insert8(ls, make_key(sm.ep.sc[sb][cl], c));
        }
        u64* dst = cand + (((size_t)sb * NT + blockIdx.x) * 4 + g) * 8;
        #pragma unroll
        for (int r = 0; r < 8; ++r) dst[r] = ls[r];
    }
    #undef WRITE_CHUNK
    #undef LOAD_CHUNK
    #undef LOAD_Q
    #undef LOAD_E
}

// ---------------------------------------------------------------------------
// Kernel 2 (merge): blocks 0..B-1: per-b merge of NT*32 candidate keys
// (contiguous 64KB, 8-deep batched) -> top-8 -> scores_out + top_idx.
// Last block: is_compressed storage-layout detection (validated rounds 1-9).
// ---------------------------------------------------------------------------
__global__ __launch_bounds__(256)
void merge_kernel(const u64* __restrict__ cand, const u32* __restrict__ mask4,
                  float* __restrict__ scores_out, int* __restrict__ top_idx,
                  int* __restrict__ flags, int C, int B, int NT) {
    const int t = threadIdx.x;

    if (blockIdx.x == (unsigned)B) {         // ---- mask layout detection ----
        __shared__ int red0[4], red1[4];
        int lo = 0, lg = 0;
        const int n4 = C >> 2;
        int i = t;
        for (; i + 768 < n4; i += 1024) {
            u32 v0 = mask4[i], v1 = mask4[i + 256], v2 = mask4[i + 512], v3 = mask4[i + 768];
            u32 o = v0 | v1 | v2 | v3;
            if (o & 0xFFFFFF00u) lo = 1;   // nonzero byte at offset 1..3
            if (o & 0xFEFEFEFEu) lg = 1;   // any byte value > 1
        }
        for (; i < n4; i += 256) {
            u32 v = mask4[i];
            if (v & 0xFFFFFF00u) lo = 1;
            if (v & 0xFEFEFEFEu) lg = 1;
        }
        const unsigned char* mb = (const unsigned char*)mask4;
        for (int j = (n4 << 2) + t; j < C; j += 256) {
            unsigned char v = mb[j];
            if (v > 1) lg = 1;
            if ((j & 3) != 0 && v != 0) lo = 1;
        }
        lo = __any(lo); lg = __any(lg);
        if ((t & 63) == 0) { red0[t >> 6] = lo; red1[t >> 6] = lg; }
        __syncthreads();
        if (t == 0) {
            flags[0] = red0[0] | red0[1] | red0[2] | red0[3];
            flags[1] = red1[0] | red1[1] | red1[2] | red1[3];
        }
        return;
    }

    __shared__ u64 sh[256 * 8];   // 16 KB
    const int b     = blockIdx.x;
    const int total = NT * 32;
    const u64* cb   = cand + (size_t)b * total;

    u64 ls[8];
    #pragma unroll
    for (int j = 0; j < 8; ++j) ls[j] = 0ull;

    int m = t;
    for (; m + 7 * 256 < total; m += 8 * 256) {    // 8 independent loads first
        u64 v[8];
        #pragma unroll
        for (int u = 0; u < 8; ++u) v[u] = cb[m + u * 256];
        #pragma unroll
        for (int u = 0; u < 8; ++u) insert8(ls, v[u]);
    }
    for (; m < total; m += 256) insert8(ls, cb[m]);

    #pragma unroll
    for (int j = 0; j < 8; ++j) sh[t * 8 + j] = ls[j];
    __syncthreads();

    if (t < 64) {
        u64 mr[8];
        #pragma unroll
        for (int j = 0; j < 8; ++j) mr[j] = 0ull;
        for (int tt = 0; tt < 4; ++tt) {
            const u64* pp = &sh[(t * 4 + tt) * 8];
            #pragma unroll
            for (int j = 0; j < 8; ++j) {
                u64 k = pp[j];
                if (k <= mr[7]) break;          // pp[] sorted descending
                mr[7] = k;
                #pragma unroll
                for (int q = 7; q > 0; --q)
                    if (mr[q] > mr[q-1]) { u64 tmp = mr[q]; mr[q] = mr[q-1]; mr[q-1] = tmp; }
            }
        }
        for (int r = 0; r < 8; ++r) {
            u64 best = mr[0];
            #pragma unroll
            for (int off = 32; off; off >>= 1) {
                u64 o = __shfl_xor(best, off, 64);
                if (o > best) best = o;
            }
            if (mr[0] == best) {                // unique owner pops
                #pragma unroll
                for (int q = 0; q < 7; ++q) mr[q] = mr[q+1];
                mr[7] = 0ull;
            }
            if (t == 0) {
                scores_out[b * 8 + r] = key_val(best);
                top_idx[b * 8 + r]    = key_idx(best);
            }
        }
    }
}

// ---------------------------------------------------------------------------
// Kernel 3 (gather): FOUR blocks per (b, j): quarter episode each (512 f4,
// 2 f4/thread). Compressed: quarters 0-1 = payload, 2-3 = zeros.
// ---------------------------------------------------------------------------
__global__ __launch_bounds__(256)
void gather_kernel(const float* __restrict__ episodes,    // [C][S][256]
                   const float* __restrict__ compressed,  // [C][Cs][256]
                   const void* __restrict__ is_comp,
                   const int* __restrict__ top_idx,       // [B*8]
                   const int* __restrict__ flags,
                   float* __restrict__ out,               // [B*8][S*256]
                   int S, int Cs) {
    const int bj  = blockIdx.x >> 2;
    const int qtr = blockIdx.x & 3;
    const int idx = top_idx[bj];
    const int f_off = flags[0], f_gt1 = flags[1];

    bool comp;
    if      (f_gt1) comp = ((const float*)is_comp)[idx] != 0.f;
    else if (f_off) comp = ((const unsigned char*)is_comp)[idx] != 0;
    else            comp = ((const int*)is_comp)[idx] != 0;

    const int n4    = S * H4;      // 2048
    const int c4    = Cs * H4;     // 1024
    const int qlen  = n4 >> 2;     // 512
    const int v0    = qtr * qlen;

    const float4* full4 = (const float4*)episodes   + (size_t)idx * n4;
    const float4* cmp4  = (const float4*)compressed + (size_t)idx * c4;
    float4* out4 = (float4*)out + (size_t)bj * n4;
    const float4 z = make_float4(0.f, 0.f, 0.f, 0.f);

    if (comp) {
        #pragma unroll 2
        for (int v = v0 + threadIdx.x; v < v0 + qlen; v += 256)
            out4[v] = (v < c4) ? cmp4[v] : z;
    } else {
        #pragma unroll 2
        for (int v = v0 + threadIdx.x; v < v0 + qlen; v += 256)
            out4[v] = full4[v];
    }
}

// ---------------------------------------------------------------------------
extern "C" void kernel_launch(void* const* d_in, const int* in_sizes, int n_in,
                              void* d_out, int out_size, void* d_ws, size_t ws_size,
                              hipStream_t stream) {
    const float* query      = (const float*)d_in[0];
    const float* episodes   = (const float*)d_in[1];
    const float* compressed = (const float*)d_in[2];
    const float* emb        = (const float*)d_in[3];
    const void*  is_comp    = d_in[4];
    // d_in[5] is k (device scalar); fixed at 8 by the problem setup.

    const int B  = in_sizes[0] / HDIM;        // 64
    const int C  = in_sizes[3] / HDIM;        // 20000
    const int S  = in_sizes[1] / (C * HDIM);  // 32
    const int Cs = in_sizes[2] / (C * HDIM);  // 16
    const int K  = 8;
    const int NT = (C + CT - 1) / CT;         // 250

    float* out        = (float*)d_out;
    float* scores_out = out + (size_t)B * K * S * HDIM;

    // scratch layout in d_ws (fully rewritten every call -> deterministic):
    u64*  cand    = (u64*)d_ws;                          // B*NT*32 u64 = 4.1 MB
    int*  top_idx = (int*)(cand + (size_t)B * NT * 32);  // B*K ints
    int*  flags   = top_idx + B * K;                     // 2 ints

    sims_topk_kernel<<<NT, 256, 0, stream>>>(
        (const float4*)query, (const float4*)emb, cand, C, B, NT);
    merge_kernel<<<B + 1, 256, 0, stream>>>(cand, (const u32*)is_comp,
                                            scores_out, top_idx, flags, C, B, NT);
    gather_kernel<<<B * K * 4, 256, 0, stream>>>(episodes, compressed, is_comp,
                                                 top_idx, flags, out, S, Cs);
}